// Round 5
// baseline (70.249 us; speedup 1.0000x reference)
//
#include <hip/hip_runtime.h>

// ---------------- problem constants ----------------
#define NBLK   98304     // 8*3*64*64 total 8x8 blocks
#define NPB    12288     // blocks per batch (3*64*64)
#define HW     512
#define NUMBITS 4096
#define RANK0  29490     // floor(0.3*(NBLK-1))
#define RANK1  29491
#define STEGO_N 6291456  // 8*3*512*512
#define ELIG   111       // ceil(4096/37) blocks contain eligible coefficients
#define HIST   16384
#define CCAP   2048
#define NWG    384       // k_stats workgroups

typedef unsigned long long ull;

// ---------------- DCT matrix as compile-time constants ----------------
struct DTab { double d[8][8]; };

constexpr double CT_[9] = {
  1.0,
  0.98078528040323044913,
  0.92387953251128675613,
  0.83146961230254523708,
  0.70710678118654752440,
  0.55557023301960222474,
  0.38268343236508977173,
  0.19509032201612826785,
  0.0
};
constexpr double cospi16(int m){           // cos(pi*m/16), m >= 0
  int r = m % 32;
  return (r<=8) ? CT_[r] : (r<=16) ? -CT_[16-r] : (r<=24) ? -CT_[r-16] : CT_[32-r];
}
constexpr DTab make_dtab(){
  DTab t{};
  for(int k=0;k<8;k++) for(int n=0;n<8;n++){
    double s = (k==0) ? 0.35355339059327376220 : 0.5; // sqrt(1/8), sqrt(2/8)
    t.d[k][n] = s * cospi16((2*n+1)*k);
  }
  return t;
}
constexpr DTab DT = make_dtab();

constexpr ull make_fmask(){ // bit u*8+v set iff 3 <= u+v <= 8
  ull m = 0;
  for(int u=0;u<8;u++) for(int v=0;v<8;v++){
    int s=u+v; if(s>=3 && s<=8) m |= (1ULL << (u*8+v));
  }
  return m;
}
constexpr ull FMASK = make_fmask();  // 37 bits set

// ---------------- kernels ----------------

// fused: stego = cover (copy), map = 0, per-block fp64 variance,
// per-WG min/max partials (no atomics)
__global__ __launch_bounds__(256) void k_stats(const float* __restrict__ cover,
    float* __restrict__ out, double* __restrict__ var,
    ull* __restrict__ wgmn, ull* __restrict__ wgmx){
  int tid = threadIdx.x;
  int i = blockIdx.x*256 + tid;             // block id over (b,c,n,m)
  int m = i & 63, n = (i>>6)&63, bc = i>>12;
  const float* p  = cover + ((size_t)bc*HW + (size_t)n*8)*HW + (size_t)m*8;
  float*       po = out   + ((size_t)bc*HW + (size_t)n*8)*HW + (size_t)m*8;
  double s1=0.0, s2=0.0;
#pragma unroll
  for(int r=0;r<8;r++){
    const float4* q = (const float4*)(p + (size_t)r*HW);
    float4 a = q[0], b = q[1];
    float4* w = (float4*)(po + (size_t)r*HW);
    w[0]=a; w[1]=b;
    double x;
    x=(double)a.x; s1+=x; s2+=x*x;
    x=(double)a.y; s1+=x; s2+=x*x;
    x=(double)a.z; s1+=x; s2+=x*x;
    x=(double)a.w; s1+=x; s2+=x*x;
    x=(double)b.x; s1+=x; s2+=x*x;
    x=(double)b.y; s1+=x; s2+=x*x;
    x=(double)b.z; s1+=x; s2+=x*x;
    x=(double)b.w; s1+=x; s2+=x*x;
  }
  double mean = s1*(1.0/64.0);
  double v = s2*(1.0/64.0) - mean*mean;
  if(v < 0.0) v = 0.0;
  var[i] = v;
  // zero the embedding map for this block (fixed up later for eligible blocks)
  float4 z = make_float4(0.f,0.f,0.f,0.f);
  float4* pm = (float4*)(out + (size_t)STEGO_N + (size_t)i*64);
#pragma unroll
  for(int j=0;j<16;j++) pm[j] = z;
  // per-WG min/max of variance bits (var>=0 so u64 bit order == value order)
  __shared__ ull smn[256], smx[256];
  ull bits = (ull)__double_as_longlong(v);
  smn[tid]=bits; smx[tid]=bits;
  __syncthreads();
  for(int off=128; off>0; off>>=1){
    if(tid<off){
      if(smn[tid+off] < smn[tid]) smn[tid]=smn[tid+off];
      if(smx[tid+off] > smx[tid]) smx[tid]=smx[tid+off];
    }
    __syncthreads();
  }
  if(tid==0){ wgmn[blockIdx.x]=smn[0]; wgmx[blockIdx.x]=smx[0]; }
}

__device__ __forceinline__ int binof(double v, double mn, double scale){
  int b = (int)((v - mn) * scale);          // sub, mul, trunc — deterministic
  if(b > HIST-1) b = HIST-1;
  if(b < 0) b = 0;
  return b;
}

// ONE workgroup does everything after variance:
// minmax -> 16K-bin LDS hist (pass 1) -> rank bins -> gather candidates (pass 2)
// -> exact rank select -> threshold -> chunked ballot scan (stops at 111th
// selected block) -> 16-wave shuffle-DCT fp64 embed of <=111 blocks.
__global__ __launch_bounds__(1024) void k_selembed(const float* __restrict__ cover,
    const int* __restrict__ secret, const double* __restrict__ var,
    const ull* __restrict__ wgmn, const ull* __restrict__ wgmx,
    float* __restrict__ out){
  __shared__ ull sA[1024];                  // 8 KB  (min tree)
  __shared__ ull sB[1024];                  // 8 KB  (max tree)
  __shared__ unsigned h[HIST];              // 64 KB (histogram)
  __shared__ unsigned sscan[1024];          // 4 KB
  __shared__ ull cand[CCAP];                // 16 KB
  __shared__ int queue[ELIG];
  __shared__ unsigned wcnt[16];
  __shared__ double sAB[2];
  __shared__ int sdesc[4];                  // b0, b1, Cb, cand_cnt
  int tid = threadIdx.x;

  // --- minmax from the 384 per-WG partials ---
  ull a = (tid < NWG) ? wgmn[tid] : 0xFFFFFFFFFFFFFFFFULL;
  ull b = (tid < NWG) ? wgmx[tid] : 0ULL;
  sA[tid]=a; sB[tid]=b;
  __syncthreads();
  for(int off=512; off>0; off>>=1){
    if(tid<off){
      if(sA[tid+off] < sA[tid]) sA[tid]=sA[tid+off];
      if(sB[tid+off] > sB[tid]) sB[tid]=sB[tid+off];
    }
    __syncthreads();
  }
  double mn = __longlong_as_double((long long)sA[0]);
  double mx = __longlong_as_double((long long)sB[0]);
  double range = mx - mn;
  double scale = (range > 0.0) ? ((double)HIST / range) : 0.0;
  for(int j=tid;j<HIST;j+=1024) h[j]=0u;
  if(tid==0) sdesc[3]=0;
  __syncthreads();

  // --- pass 1: 16K-bin histogram over var ---
  const double4* v4 = (const double4*)var;  // 24576 double4
#pragma unroll 4
  for(int j=0;j<24;j++){
    double4 v = v4[j*1024 + tid];
    atomicAdd(&h[binof(v.x, mn, scale)], 1u);
    atomicAdd(&h[binof(v.y, mn, scale)], 1u);
    atomicAdd(&h[binof(v.z, mn, scale)], 1u);
    atomicAdd(&h[binof(v.w, mn, scale)], 1u);
  }
  __syncthreads();

  // --- locate the bins holding RANK0/RANK1 + count below b0 ---
  int base = tid*16;
  unsigned ls = 0;
#pragma unroll
  for(int k=0;k<16;k++) ls += h[base+k];
  sscan[tid]=ls; __syncthreads();
  for(int off=1;off<1024;off<<=1){
    unsigned add = (tid>=off)? sscan[tid-off] : 0u;
    __syncthreads();
    sscan[tid]+=add;
    __syncthreads();
  }
  unsigned incl = sscan[tid], excl = incl - ls;
  if((unsigned)RANK0 >= excl && (unsigned)RANK0 < incl){
    unsigned c = excl;
    for(int k=0;k<16;k++){
      unsigned bc = h[base+k];
      if((unsigned)RANK0 < c+bc){ sdesc[0]=base+k; sdesc[2]=(int)c; break; }
      c += bc;
    }
  }
  if((unsigned)RANK1 >= excl && (unsigned)RANK1 < incl){
    unsigned c = excl;
    for(int k=0;k<16;k++){
      unsigned bc = h[base+k];
      if((unsigned)RANK1 < c+bc){ sdesc[1]=base+k; break; }
      c += bc;
    }
  }
  __syncthreads();
  int b0=sdesc[0], b1=sdesc[1], Cb=sdesc[2];

  // --- pass 2: gather candidate bit-patterns from bins [b0,b1] ---
#pragma unroll 4
  for(int j=0;j<24;j++){
    double4 v = v4[j*1024 + tid];
    double vv[4] = {v.x, v.y, v.z, v.w};
#pragma unroll
    for(int e=0;e<4;e++){
      int bn = binof(vv[e], mn, scale);
      if(bn >= b0 && bn <= b1){
        int idx = atomicAdd(&sdesc[3], 1);
        if(idx < CCAP) cand[idx] = (ull)__double_as_longlong(vv[e]);
      }
    }
  }
  __syncthreads();

  // --- exact rank select among candidates ---
  int K = sdesc[3]; if(K > CCAP) K = CCAP;
  int r0 = RANK0 - Cb, r1 = RANK1 - Cb;
  for(int t=tid; t<K; t+=1024){
    ull x = cand[t];
    int cl=0, ce=0;
    for(int j2=0;j2<K;j2++){ ull y=cand[j2]; cl += (y<x); ce += (y==x); }
    if(cl<=r0 && r0<cl+ce) sAB[0]=__longlong_as_double((long long)x);
    if(cl<=r1 && r1<cl+ce) sAB[1]=__longlong_as_double((long long)x);
  }
  __syncthreads();
  double A=sAB[0], Bv=sAB[1];
  double thr = A + 0.9*(Bv - A);   // selection: var_norm>thr <=> var>thr_raw

  // --- chunked ballot scan in index order; stop once ELIG blocks queued ---
  int wid = tid>>6, lane = tid&63;
  int total = 0;
  for(int chunk=0; chunk<96; chunk++){
    int i = chunk*1024 + tid;
    int f = (var[i] > thr) ? 1 : 0;
    ull bal = __ballot(f);
    if(lane==0) wcnt[wid] = (unsigned)__popcll(bal);
    __syncthreads();
    int wpre=0, csum=0;
#pragma unroll
    for(int w=0;w<16;w++){
      int c = (int)wcnt[w];
      if(w<wid) wpre += c;
      csum += c;
    }
    int P = total + wpre + (int)__popcll(bal & ((1ULL<<lane)-1ULL));
    if(f && P < ELIG) queue[P] = i;   // S == slot index, no atomics
    total += csum;
    __syncthreads();
    if(total >= ELIG) break;
  }
  int nq = (total < ELIG) ? total : ELIG;

  // --- embed: wave w handles queue[w], queue[w+16], ... (fp64 shuffle DCT) ---
  int lr = lane>>3, lc = lane&7;
  for(int q = wid; q < nq; q += 16){
    int bi = queue[q], S2 = q;
    int m = bi & 63, n = (bi>>6)&63, bc = bi>>12, bb = bi / NPB;
    const float* p  = cover + ((size_t)bc*HW + (size_t)n*8)*HW + (size_t)m*8;
    float*       po = out   + ((size_t)bc*HW + (size_t)n*8)*HW + (size_t)m*8;
    double x = (double)p[(size_t)lr*HW + lc];     // X[lr][lc]
    // stage1: T1[r][v] = sum_j X[r][j]*D[v][j]
    double t1 = 0.0;
#pragma unroll
    for(int j=0;j<8;j++) t1 += __shfl(x, lr*8+j) * DT.d[lc][j];
    // stage2: C[u][v] = sum_k D[u][k]*T1[k][v]
    double coef = 0.0;
#pragma unroll
    for(int k=0;k<8;k++) coef += DT.d[lr][k] * __shfl(t1, k*8+lc);
    // embedding
    bool sel = (FMASK>>lane)&1ULL;
    float mv = 0.f;
    if(sel){
      int fp  = (int)__popcll(FMASK & ((1ULL<<lane)-1ULL));
      int ord = 37*S2 + fp;
      if(ord < NUMBITS){
        mv = 1.f;
        double rnd = rint(coef);                  // round half-to-even == jnp.round
        int lsb = ((int)fabs(rnd)) & 1;
        int bit = secret[(size_t)bb*NUMBITS + ord];
        if(lsb != bit) coef += ((coef>=0.0)?1.0:-1.0)*(2.0*(double)bit-1.0)*0.5;
      }
    }
    out[(size_t)STEGO_N + (size_t)bi*64 + lane] = mv;
    // inv stage1: T2[r][v] = sum_u D[u][r]*M[u][v]
    double t2 = 0.0;
#pragma unroll
    for(int u=0;u<8;u++) t2 += DT.d[u][lr] * __shfl(coef, u*8+lc);
    // inv stage2: pix[r][k] = sum_q T2[r][q]*D[q][k]
    double px = 0.0;
#pragma unroll
    for(int qq=0;qq<8;qq++) px += __shfl(t2, lr*8+qq) * DT.d[qq][lc];
    po[(size_t)lr*HW + lc] = (float)px;
  }
}

// ---------------- host launch ----------------
extern "C" void kernel_launch(void* const* d_in, const int* in_sizes, int n_in,
                              void* d_out, int out_size, void* d_ws, size_t ws_size,
                              hipStream_t stream) {
  const float* cover  = (const float*)d_in[0];
  const int*   secret = (const int*)d_in[1];
  float* out = (float*)d_out;
  char*  ws  = (char*)d_ws;

  // ws layout (bytes)
  double* var  = (double*)(ws);               // 98304*8 = 786432
  ull*    wgmn = (ull*)(ws + 786432);         // 384*8   -> 789504
  ull*    wgmx = (ull*)(ws + 789504);         // 384*8   -> 792576

  k_stats   <<<NWG, 256, 0, stream>>>(cover, out, var, wgmn, wgmx);
  k_selembed<<<1, 1024, 0, stream>>>(cover, secret, var, wgmn, wgmx, out);
}